// Round 7
// baseline (2265.717 us; speedup 1.0000x reference)
//
#include <hip/hip_runtime.h>
#include <stdint.h>

#define NSEQ 512
#define XS 328   // xin row stride (shorts): [0:64 z_hi][64:128 z_lo][128:224 c_hi][224:320 c_lo]
#define AS 136   // act row stride (shorts)
#define PS 36    // part row stride (f32)
#define EPS 1e-5f

typedef short bfrag __attribute__((ext_vector_type(8)));
typedef float f4 __attribute__((ext_vector_type(4)));

#define MFMA16 __builtin_amdgcn_mfma_f32_16x16x32_bf16

__device__ __forceinline__ float lo16f(uint32_t u){ return __uint_as_float(u<<16); }
__device__ __forceinline__ float hi16f(uint32_t u){ return __uint_as_float(u & 0xFFFF0000u); }
__device__ __forceinline__ unsigned short f2bf(float f){
  uint32_t u = __float_as_uint(f);
  u += 0x7FFFu + ((u>>16)&1u);   // RNE
  return (unsigned short)(u>>16);
}
__device__ __forceinline__ uint32_t pk2bf(float a, float b){
  uint32_t r;
  asm("v_cvt_pk_bf16_f32 %0, %1, %2" : "=v"(r) : "v"(a), "v"(b));
  return r;
}
__device__ __forceinline__ float tanh_fast(float v){
  float e = __builtin_amdgcn_exp2f(v * 2.8853900817779268f);  // e^(2v)
  float r = __builtin_amdgcn_rcpf(e + 1.f);
  return fmaf(-2.f, r, 1.f);
}
__device__ __forceinline__ void lds_barrier(){
  asm volatile("s_waitcnt lgkmcnt(0)" ::: "memory");
  __builtin_amdgcn_s_barrier();
  asm volatile("" ::: "memory");
}

__device__ __forceinline__ void stats_write(const float (&h0)[4], const float (&h1)[4],
                                            float* __restrict__ part_g,
                                            const int w, const int lg, const int lc){
  const float s = ((h0[0]+h0[1])+(h0[2]+h0[3])) + ((h1[0]+h1[1])+(h1[2]+h1[3]));
  const float q = (fmaf(h0[0],h0[0], h0[1]*h0[1]) + fmaf(h0[2],h0[2], h0[3]*h0[3]))
                + (fmaf(h1[0],h1[0], h1[1]*h1[1]) + fmaf(h1[2],h1[2], h1[3]*h1[3]));
  *(float2*)(part_g + lc*PS + (w*4+lg)*2) = make_float2(s, q);
}

__device__ __forceinline__ void ln_tanh_store(const float (&h0)[4], const float (&h1)[4],
    const float (&gd)[2][4], const float (&bed)[2][4],
    const float* __restrict__ part_g, unsigned short* __restrict__ act_g,
    const int w, const int lg, const int lc){
  const float* pr = part_g + lc*PS;
  const f4 p0=*(const f4*)(pr),    p1=*(const f4*)(pr+4),  p2=*(const f4*)(pr+8),  p3=*(const f4*)(pr+12);
  const f4 p4=*(const f4*)(pr+16), p5=*(const f4*)(pr+20), p6=*(const f4*)(pr+24), p7=*(const f4*)(pr+28);
  const float ss = (((p0.x+p0.z)+(p1.x+p1.z)) + ((p2.x+p2.z)+(p3.x+p3.z)))
                 + (((p4.x+p4.z)+(p5.x+p5.z)) + ((p6.x+p6.z)+(p7.x+p7.z)));
  const float qq = (((p0.y+p0.w)+(p1.y+p1.w)) + ((p2.y+p2.w)+(p3.y+p3.w)))
                 + (((p4.y+p4.w)+(p5.y+p5.w)) + ((p6.y+p6.w)+(p7.y+p7.w)));
  const float mu = ss * 0.0078125f;
  const float rs = rsqrtf(fmaf(qq, 0.0078125f, -mu*mu) + EPS);
  float e0[4], e1[4];
#pragma unroll
  for (int g=0; g<4; ++g){
    e0[g] = tanh_fast(fmaf((h0[g]-mu)*rs, gd[0][g], bed[0][g]));
    e1[g] = tanh_fast(fmaf((h1[g]-mu)*rs, gd[1][g], bed[1][g]));
  }
  uint4 pk4;
  pk4.x = pk2bf(e0[0],e0[1]); pk4.y = pk2bf(e0[2],e0[3]);
  pk4.z = pk2bf(e1[0],e1[1]); pk4.w = pk2bf(e1[2],e1[3]);
  *(uint4*)(act_g + lc*AS + w*32 + lg*8) = pk4;
}

// L0 z-part (hi/lo) + pre-acc combine + stats
__device__ __forceinline__ void sec_L0(
    const unsigned short* __restrict__ xin_g, float* __restrict__ part_g,
    const bfrag (&A0z)[2][4], const float (&bd0)[2][4],
    const f4 (&apC)[2], const f4 (&apE)[2],
    float (&h0)[4], float (&h1)[4],
    const int w, const int lg, const int lc){
  bfrag bz[4];
  const int zoff = lc*XS + lg*8;
#pragma unroll
  for (int kt=0; kt<4; ++kt) bz[kt] = *(const bfrag*)(xin_g + zoff + kt*32);
  f4 c0a={0,0,0,0}, c0b={0,0,0,0}, c1a={0,0,0,0}, c1b={0,0,0,0};
  c0a = MFMA16(A0z[0][0], bz[0], c0a,0,0,0);
  c0b = MFMA16(A0z[0][1], bz[1], c0b,0,0,0);
  c1a = MFMA16(A0z[1][0], bz[0], c1a,0,0,0);
  c1b = MFMA16(A0z[1][1], bz[1], c1b,0,0,0);
  c0a = MFMA16(A0z[0][2], bz[2], c0a,0,0,0);
  c0b = MFMA16(A0z[0][3], bz[3], c0b,0,0,0);
  c1a = MFMA16(A0z[1][2], bz[2], c1a,0,0,0);
  c1b = MFMA16(A0z[1][3], bz[3], c1b,0,0,0);
#pragma unroll
  for (int g=0; g<4; ++g){
    h0[g] = ((c0a[g]+c0b[g]) + (apC[0][g]+apE[0][g])) + bd0[0][g];
    h1[g] = ((c1a[g]+c1b[g]) + (apC[1][g]+apE[1][g])) + bd0[1][g];
  }
  stats_write(h0, h1, part_g, w, lg, lc);
}

// K=128 hidden layer MFMA + stats (L1/L2)
__device__ __forceinline__ void sec_K128(
    const unsigned short* __restrict__ act_g, float* __restrict__ part_g,
    const bfrag (&Af)[2][4], const float (&bd)[2][4],
    float (&h0)[4], float (&h1)[4],
    const int w, const int lg, const int lc){
  bfrag ba[4];
  const int aoff = lc*AS + lg*8;
#pragma unroll
  for (int kt=0; kt<4; ++kt) ba[kt] = *(const bfrag*)(act_g + aoff + kt*32);
  f4 c0a={0,0,0,0}, c0b={0,0,0,0}, c1a={0,0,0,0}, c1b={0,0,0,0};
  c0a = MFMA16(Af[0][0], ba[0], c0a,0,0,0);
  c0b = MFMA16(Af[0][1], ba[1], c0b,0,0,0);
  c1a = MFMA16(Af[1][0], ba[0], c1a,0,0,0);
  c1b = MFMA16(Af[1][1], ba[1], c1b,0,0,0);
  c0a = MFMA16(Af[0][2], ba[2], c0a,0,0,0);
  c0b = MFMA16(Af[0][3], ba[3], c0b,0,0,0);
  c1a = MFMA16(Af[1][2], ba[2], c1a,0,0,0);
  c1b = MFMA16(Af[1][3], ba[3], c1b,0,0,0);
#pragma unroll
  for (int g=0; g<4; ++g){
    h0[g] = (c0a[g]+c0b[g]) + bd[0][g];
    h1[g] = (c1a[g]+c1b[g]) + bd[1][g];
  }
  stats_write(h0, h1, part_g, w, lg, lc);
}

// pre-acc 3 cond slots starting at A0c[.][S0], xin byte-region BASE
template<int S0, int BASE>
__device__ __forceinline__ void preacc3(
    const unsigned short* __restrict__ xin_g,
    const bfrag (&A0c)[2][6], f4 (&ap)[2], const int lg, const int lc){
  const bfrag bc0 = *(const bfrag*)(xin_g + lc*XS + BASE      + lg*8);
  const bfrag bc1 = *(const bfrag*)(xin_g + lc*XS + BASE + 32 + lg*8);
  const bfrag bc2 = *(const bfrag*)(xin_g + lc*XS + BASE + 64 + lg*8);
  f4 a0={0,0,0,0}, a1={0,0,0,0};
  a0 = MFMA16(A0c[0][S0+0], bc0, a0,0,0,0);
  a1 = MFMA16(A0c[1][S0+0], bc0, a1,0,0,0);
  a0 = MFMA16(A0c[0][S0+1], bc1, a0,0,0,0);
  a1 = MFMA16(A0c[1][S0+1], bc1, a1,0,0,0);
  a0 = MFMA16(A0c[0][S0+2], bc2, a0,0,0,0);
  a1 = MFMA16(A0c[1][S0+2], bc2, a1,0,0,0);
  ap[0]=a0; ap[1]=a1;
}

// stage cond(i+1) from pf regs; reload pf = cond(i+2)
__device__ __forceinline__ void stage_cond(
    unsigned short* __restrict__ xin_g, float2 (&pf)[3],
    const float* __restrict__ cbase, const int srow, const int sq, const int i){
#pragma unroll
  for (int k2=0; k2<3; ++k2){
    const int s2 = (sq + 16*k2)*2;
    const uint32_t uh = pk2bf(pf[k2].x, pf[k2].y);
    *(uint32_t*)(xin_g + srow*XS + 128 + s2) = uh;
    *(uint32_t*)(xin_g + srow*XS + 224 + s2) = pk2bf(pf[k2].x - lo16f(uh), pf[k2].y - hi16f(uh));
  }
  if (i < NSEQ-2){
#pragma unroll
    for (int k2=0; k2<3; ++k2)
      pf[k2] = *(const float2*)(cbase + (size_t)(i+2)*96 + (sq + 16*k2)*2);
  }
}

// output layer + Euler + out/xin stores
__device__ __forceinline__ void sec_out(
    const unsigned short* __restrict__ act_g, unsigned short* __restrict__ xin_g,
    const bfrag (&Aof)[4], const float (&bo_d)[4],
    f4& zr, const float dtv, float* __restrict__ out,
    const int rg, const int zcol, const int lg, const int lc, const int i){
  bfrag ba[4];
  const int aoff = lc*AS + lg*8;
#pragma unroll
  for (int kt=0; kt<4; ++kt) ba[kt] = *(const bfrag*)(act_g + aoff + kt*32);
  f4 aa={0,0,0,0}, ab={0,0,0,0};
  aa = MFMA16(Aof[0], ba[0], aa,0,0,0);
  ab = MFMA16(Aof[1], ba[1], ab,0,0,0);
  aa = MFMA16(Aof[2], ba[2], aa,0,0,0);
  ab = MFMA16(Aof[3], ba[3], ab,0,0,0);
  f4 zn;
#pragma unroll
  for (int g=0; g<4; ++g) zn[g] = fmaf(dtv, (aa[g]+ab[g]) + bo_d[g], zr[g]);
  zr = zn;
  *(f4*)(out + ((size_t)(rg+lc)*NSEQ + (size_t)(i+1))*64 + zcol) = zn;
  const uint32_t u01 = pk2bf(zn[0],zn[1]), u23 = pk2bf(zn[2],zn[3]);
  const uint32_t l01 = pk2bf(zn[0]-lo16f(u01), zn[1]-hi16f(u01));
  const uint32_t l23 = pk2bf(zn[2]-lo16f(u23), zn[3]-hi16f(u23));
  *(uint2*)(xin_g + lc*XS + zcol)      = make_uint2(u01,u23);
  *(uint2*)(xin_g + lc*XS + 64 + zcol) = make_uint2(l01,l23);
}

__global__ __launch_bounds__(256, 1)
void latent_ode_v7(const float* __restrict__ z0, const float* __restrict__ tt,
                   const float* __restrict__ cond,
                   const float* __restrict__ W0, const float* __restrict__ b0,
                   const float* __restrict__ g0, const float* __restrict__ be0,
                   const float* __restrict__ W1, const float* __restrict__ b1,
                   const float* __restrict__ g1, const float* __restrict__ be1,
                   const float* __restrict__ W2, const float* __restrict__ b2,
                   const float* __restrict__ g2, const float* __restrict__ be2,
                   const float* __restrict__ Wo, const float* __restrict__ bo,
                   float* __restrict__ out)
{
  __shared__ __align__(16) unsigned short xinA[16*XS], xinB[16*XS];
  __shared__ __align__(16) unsigned short actA[16*AS], actB[16*AS];
  __shared__ __align__(16) float partA[16*PS], partB[16*PS];

  const int t  = threadIdx.x;
  const int w  = t >> 6;
  const int l  = t & 63;
  const int lg = l >> 4;
  const int lc = l & 15;
  const int rA = blockIdx.x * 32;
  const int rB = rA + 16;
  const int zcol = w*16 + lg*4;

  // ---- weight fragments (shared by both groups). Row permutation as v6.
  bfrag A0z[2][4], A0c[2][6], A1f[2][4], A2f[2][4], Aof[4];
#pragma unroll
  for (int nt=0; nt<2; ++nt){
    const int col = w*32 + nt*4 + ((lc>>2)<<3) + (lc&3);
#pragma unroll
    for (int kt=0; kt<4; ++kt){
      union { bfrag v; unsigned short u[8]; } r;
#pragma unroll
      for (int j=0; j<8; ++j)
        r.u[j] = f2bf(W0[(size_t)((kt&1)*32 + lg*8 + j)*128 + col]);
      A0z[nt][kt] = r.v;
    }
#pragma unroll
    for (int s=0; s<6; ++s){
      const int sm = (s<3)? s : s-3;
      union { bfrag v; unsigned short u[8]; } r;
#pragma unroll
      for (int j=0; j<8; ++j)
        r.u[j] = f2bf(W0[(size_t)(64 + sm*32 + lg*8 + j)*128 + col]);
      A0c[nt][s] = r.v;
    }
#pragma unroll
    for (int kt=0; kt<4; ++kt){
      union { bfrag v; unsigned short u[8]; } r1, r2;
#pragma unroll
      for (int j=0; j<8; ++j){
        const int k = kt*32 + lg*8 + j;
        r1.u[j] = f2bf(W1[(size_t)k*128 + col]);
        r2.u[j] = f2bf(W2[(size_t)k*128 + col]);
      }
      A1f[nt][kt] = r1.v; A2f[nt][kt] = r2.v;
    }
  }
#pragma unroll
  for (int kt=0; kt<4; ++kt){
    union { bfrag v; unsigned short u[8]; } r;
#pragma unroll
    for (int j=0; j<8; ++j)
      r.u[j] = f2bf(Wo[(size_t)(kt*32 + lg*8 + j)*64 + (w*16 + lc)]);
    Aof[kt] = r.v;
  }
  float bd0[2][4], gd0[2][4], bed0[2][4];
  float bd1[2][4], gd1[2][4], bed1[2][4];
  float bd2[2][4], gd2[2][4], bed2[2][4];
  float bo_d[4];
#pragma unroll
  for (int nt=0; nt<2; ++nt){
#pragma unroll
    for (int g=0; g<4; ++g){
      const int n = w*32 + lg*8 + nt*4 + g;
      bd0[nt][g]=b0[n]; gd0[nt][g]=g0[n]; bed0[nt][g]=be0[n];
      bd1[nt][g]=b1[n]; gd1[nt][g]=g1[n]; bed1[nt][g]=be1[n];
      bd2[nt][g]=b2[n]; gd2[nt][g]=g2[n]; bed2[nt][g]=be2[n];
    }
  }
#pragma unroll
  for (int g=0; g<4; ++g) bo_d[g] = bo[zcol + g];

  // ---- time pipeline (registers; one load/step/group)
  const float* tpA = tt + (size_t)(rA+lc)*NSEQ;
  const float* tpB = tt + (size_t)(rB+lc)*NSEQ;
  float tcA = tpA[0], tnA = tpA[1];
  float tcB = tpB[0], tnB = tpB[1];

  // ---- z init both groups
  f4 zrA, zrB;
  {
    const f4 zv = *(const f4*)(z0 + (size_t)(rA+lc)*64 + zcol);
    zrA = zv;
    *(f4*)(out + ((size_t)(rA+lc)*NSEQ)*64 + zcol) = zv;
    const uint32_t u01 = pk2bf(zv[0],zv[1]), u23 = pk2bf(zv[2],zv[3]);
    const uint32_t l01 = pk2bf(zv[0]-lo16f(u01), zv[1]-hi16f(u01));
    const uint32_t l23 = pk2bf(zv[2]-lo16f(u23), zv[3]-hi16f(u23));
    *(uint2*)(xinA + lc*XS + zcol)      = make_uint2(u01,u23);
    *(uint2*)(xinA + lc*XS + 64 + zcol) = make_uint2(l01,l23);
  }
  {
    const f4 zv = *(const f4*)(z0 + (size_t)(rB+lc)*64 + zcol);
    zrB = zv;
    *(f4*)(out + ((size_t)(rB+lc)*NSEQ)*64 + zcol) = zv;
    const uint32_t u01 = pk2bf(zv[0],zv[1]), u23 = pk2bf(zv[2],zv[3]);
    const uint32_t l01 = pk2bf(zv[0]-lo16f(u01), zv[1]-hi16f(u01));
    const uint32_t l23 = pk2bf(zv[2]-lo16f(u23), zv[3]-hi16f(u23));
    *(uint2*)(xinB + lc*XS + zcol)      = make_uint2(u01,u23);
    *(uint2*)(xinB + lc*XS + 64 + zcol) = make_uint2(l01,l23);
  }

  // ---- cond(0) staged + pf=cond(1), both groups
  const int srow = t >> 4, sq = t & 15;
  const float* cbaseA = cond + ((size_t)(rA+srow)*NSEQ)*96;
  const float* cbaseB = cond + ((size_t)(rB+srow)*NSEQ)*96;
  float2 pfA[3], pfB[3];
#pragma unroll
  for (int k2=0; k2<3; ++k2){
    const int s2 = (sq + 16*k2)*2;
    const float2 cA = *(const float2*)(cbaseA + s2);
    const uint32_t uhA = pk2bf(cA.x, cA.y);
    *(uint32_t*)(xinA + srow*XS + 128 + s2) = uhA;
    *(uint32_t*)(xinA + srow*XS + 224 + s2) = pk2bf(cA.x - lo16f(uhA), cA.y - hi16f(uhA));
    pfA[k2] = *(const float2*)(cbaseA + 96 + s2);
    const float2 cB = *(const float2*)(cbaseB + s2);
    const uint32_t uhB = pk2bf(cB.x, cB.y);
    *(uint32_t*)(xinB + srow*XS + 128 + s2) = uhB;
    *(uint32_t*)(xinB + srow*XS + 224 + s2) = pk2bf(cB.x - lo16f(uhB), cB.y - hi16f(uhB));
    pfB[k2] = *(const float2*)(cbaseB + 96 + s2);
  }
  lds_barrier();

  // ---- prologue pre-acc of cond(0), both groups
  f4 apCA[2], apEA[2], apCB[2], apEB[2];
  preacc3<0,128>(xinA, A0c, apCA, lg, lc);
  preacc3<3,224>(xinA, A0c, apEA, lg, lc);
  preacc3<0,128>(xinB, A0c, apCB, lg, lc);
  preacc3<3,224>(xinB, A0c, apEB, lg, lc);

  float h0A[4], h1A[4], h0B[4], h1B[4];
  for (int i=0; i<NSEQ-1; ++i){
    // t prefetch for step i+1 (clamped)
    const int ip2 = (i+2 <= NSEQ-1) ? (i+2) : (NSEQ-1);
    const float tfA = tpA[ip2];
    const float tfB = tpB[ip2];

    // ---- S_A: L0 z-part both groups + cond(i+1) staging both
    sec_L0(xinA, partA, A0z, bd0, apCA, apEA, h0A, h1A, w, lg, lc);
    sec_L0(xinB, partB, A0z, bd0, apCB, apEB, h0B, h1B, w, lg, lc);
    stage_cond(xinA, pfA, cbaseA, srow, sq, i);
    stage_cond(xinB, pfB, cbaseB, srow, sq, i);
    lds_barrier();

    // ---- S_B: LN0 both + pre-acc cond-hi both
    preacc3<0,128>(xinA, A0c, apCA, lg, lc);
    preacc3<0,128>(xinB, A0c, apCB, lg, lc);
    ln_tanh_store(h0A, h1A, gd0, bed0, partA, actA, w, lg, lc);
    ln_tanh_store(h0B, h1B, gd0, bed0, partB, actB, w, lg, lc);
    lds_barrier();

    // ---- S_C: L1 both
    sec_K128(actA, partA, A1f, bd1, h0A, h1A, w, lg, lc);
    sec_K128(actB, partB, A1f, bd1, h0B, h1B, w, lg, lc);
    lds_barrier();

    // ---- S_D: LN1 both + pre-acc cond-lo both
    preacc3<3,224>(xinA, A0c, apEA, lg, lc);
    preacc3<3,224>(xinB, A0c, apEB, lg, lc);
    ln_tanh_store(h0A, h1A, gd1, bed1, partA, actA, w, lg, lc);
    ln_tanh_store(h0B, h1B, gd1, bed1, partB, actB, w, lg, lc);
    lds_barrier();

    // ---- S_E: L2 both
    sec_K128(actA, partA, A2f, bd2, h0A, h1A, w, lg, lc);
    sec_K128(actB, partB, A2f, bd2, h0B, h1B, w, lg, lc);
    lds_barrier();

    // ---- S_F: LN2 both
    ln_tanh_store(h0A, h1A, gd2, bed2, partA, actA, w, lg, lc);
    ln_tanh_store(h0B, h1B, gd2, bed2, partB, actB, w, lg, lc);
    lds_barrier();

    // ---- S_G: output + Euler + stores, both
    const float dtA = tnA - tcA;
    const float dtB = tnB - tcB;
    sec_out(actA, xinA, Aof, bo_d, zrA, dtA, out, rA, zcol, lg, lc, i);
    sec_out(actB, xinB, Aof, bo_d, zrB, dtB, out, rB, zcol, lg, lc, i);
    tcA = tnA; tnA = tfA;
    tcB = tnB; tnB = tfB;
    lds_barrier();
  }
}

extern "C" void kernel_launch(void* const* d_in, const int* in_sizes, int n_in,
                              void* d_out, int out_size, void* d_ws, size_t ws_size,
                              hipStream_t stream) {
  const float* z0   = (const float*)d_in[0];
  const float* tt   = (const float*)d_in[1];
  const float* cond = (const float*)d_in[2];
  const float* W0   = (const float*)d_in[3];
  const float* b0   = (const float*)d_in[4];
  const float* g0   = (const float*)d_in[5];
  const float* be0  = (const float*)d_in[6];
  const float* W1   = (const float*)d_in[7];
  const float* b1   = (const float*)d_in[8];
  const float* g1   = (const float*)d_in[9];
  const float* be1  = (const float*)d_in[10];
  const float* W2   = (const float*)d_in[11];
  const float* b2   = (const float*)d_in[12];
  const float* g2   = (const float*)d_in[13];
  const float* be2  = (const float*)d_in[14];
  const float* Wo   = (const float*)d_in[15];
  const float* bo   = (const float*)d_in[16];
  float* out = (float*)d_out;

  hipLaunchKernelGGL(latent_ode_v7, dim3(32), dim3(256), 0, stream,
                     z0, tt, cond, W0, b0, g0, be0, W1, b1, g1, be1,
                     W2, b2, g2, be2, Wo, bo, out);
}

// Round 8
// 1126.429 us; speedup vs baseline: 2.0114x; 2.0114x over previous
//
#include <hip/hip_runtime.h>
#include <stdint.h>

#define NSEQ 512
#define XS 168    // xin row stride (shorts): [0:64 z][64:160 cond] + pad (84 dw, %32=20)
#define AS 136    // act row stride (shorts): 68 dw, %32=4
#define PS 20     // part row stride (f32): 8 float2 + pad
#define EPS 1e-5f

typedef short bfrag __attribute__((ext_vector_type(8)));
typedef float f4 __attribute__((ext_vector_type(4)));
#define MFMA16 __builtin_amdgcn_mfma_f32_16x16x32_bf16

__device__ __forceinline__ unsigned short f2bf(float f){
  uint32_t u = __float_as_uint(f);
  u += 0x7FFFu + ((u>>16)&1u);   // RNE
  return (unsigned short)(u>>16);
}
__device__ __forceinline__ uint32_t pk2bf(float a, float b){
  uint32_t r;
  asm("v_cvt_pk_bf16_f32 %0, %1, %2" : "=v"(r) : "v"(a), "v"(b));
  return r;
}
__device__ __forceinline__ float tanh_fast(float v){
  float e = __builtin_amdgcn_exp2f(v * 2.8853900817779268f);  // e^(2v)
  float r = __builtin_amdgcn_rcpf(e + 1.f);
  return fmaf(-2.f, r, 1.f);
}
// LDS-only barrier (global loads/stores stay in flight)
__device__ __forceinline__ void lds_barrier(){
  asm volatile("s_waitcnt lgkmcnt(0)" ::: "memory");
  __builtin_amdgcn_s_barrier();
  asm volatile("" ::: "memory");
}

// stats over this lane's 4 neurons; in-wave reduce over lg (xor16, xor32);
// lanes lg==0 write per-(wave,row) partial.
__device__ __forceinline__ void stats_sq(const float (&h)[4], float* __restrict__ part,
                                         const int w, const int lg, const int lc){
  float s = (h[0]+h[1])+(h[2]+h[3]);
  float q = fmaf(h[0],h[0], h[1]*h[1]) + fmaf(h[2],h[2], h[3]*h[3]);
  s += __shfl_xor(s, 16); q += __shfl_xor(q, 16);
  s += __shfl_xor(s, 32); q += __shfl_xor(q, 32);
  if (lg == 0) *(float2*)(part + lc*PS + w*2) = make_float2(s, q);
}

// LN + tanh + single uint2 act store (lane's 4 contiguous neurons)
__device__ __forceinline__ void ln_tanh_store(const float (&h)[4],
    const float (&gd)[4], const float (&bed)[4],
    const float* __restrict__ part, unsigned short* __restrict__ actb,
    const int lg, const int lc, const int nbase){
  const float* pr = part + lc*PS;
  const f4 p0 = *(const f4*)(pr);      // {s0,q0,s1,q1}
  const f4 p1 = *(const f4*)(pr + 4);
  const f4 p2 = *(const f4*)(pr + 8);
  const f4 p3 = *(const f4*)(pr + 12);
  const float ss = ((p0.x+p0.z)+(p1.x+p1.z)) + ((p2.x+p2.z)+(p3.x+p3.z));
  const float qq = ((p0.y+p0.w)+(p1.y+p1.w)) + ((p2.y+p2.w)+(p3.y+p3.w));
  const float mu = ss * 0.0078125f;
  const float rs = rsqrtf(fmaf(qq, 0.0078125f, -mu*mu) + EPS);
  float e[4];
#pragma unroll
  for (int g=0; g<4; ++g)
    e[g] = tanh_fast(fmaf((h[g]-mu)*rs, gd[g], bed[g]));
  *(uint2*)(actb + lc*AS + nbase) = make_uint2(pk2bf(e[0],e[1]), pk2bf(e[2],e[3]));
}

// K=128 hidden layer MFMAs (single n-tile per wave)
__device__ __forceinline__ void layerK128(const unsigned short* __restrict__ actb,
    const bfrag (&A)[4], const float (&bd)[4], float (&h)[4],
    const int lg, const int lc){
  const int o = lc*AS + lg*8;
  const bfrag b0 = *(const bfrag*)(actb + o);
  const bfrag b1 = *(const bfrag*)(actb + o + 32);
  const bfrag b2 = *(const bfrag*)(actb + o + 64);
  const bfrag b3 = *(const bfrag*)(actb + o + 96);
  const f4 z4 = {0,0,0,0};
  f4 ca = MFMA16(A[0], b0, z4, 0,0,0);
  f4 cb = MFMA16(A[1], b1, z4, 0,0,0);
  ca = MFMA16(A[2], b2, ca, 0,0,0);
  cb = MFMA16(A[3], b3, cb, 0,0,0);
#pragma unroll
  for (int g=0; g<4; ++g) h[g] = (ca[g]+cb[g]) + bd[g];
}

__global__ __launch_bounds__(512, 2)
void latent_ode_v8(const float* __restrict__ z0, const float* __restrict__ tt,
                   const float* __restrict__ cond,
                   const float* __restrict__ W0, const float* __restrict__ b0,
                   const float* __restrict__ g0, const float* __restrict__ be0,
                   const float* __restrict__ W1, const float* __restrict__ b1,
                   const float* __restrict__ g1, const float* __restrict__ be1,
                   const float* __restrict__ W2, const float* __restrict__ b2,
                   const float* __restrict__ g2, const float* __restrict__ be2,
                   const float* __restrict__ Wo, const float* __restrict__ bo,
                   float* __restrict__ out)
{
  __shared__ __align__(16) unsigned short xin[16*XS];
  __shared__ __align__(16) unsigned short act[16*AS];
  __shared__ __align__(16) float part[16*PS];

  const int t  = threadIdx.x;     // 0..511
  const int w  = t >> 6;          // 0..7
  const int l  = t & 63;
  const int lg = l >> 4;
  const int lc = l & 15;
  const int r0 = blockIdx.x * 16;
  const int ncol  = w*16 + lc;    // weight col (hidden layers)
  const int nbase = w*16 + lg*4;  // lane's first neuron
  const bool loW = (w < 4);       // Lo/Euler/t-pipeline waves

  // ---- weight fragments (plain bf16, no lo parts)
  bfrag A0z[2], A0c[3], A1f[4], A2f[4], Aof[4];
#pragma unroll
  for (int kt=0; kt<2; ++kt){
    union { bfrag v; unsigned short u[8]; } r;
#pragma unroll
    for (int j=0; j<8; ++j) r.u[j] = f2bf(W0[(size_t)(kt*32 + lg*8 + j)*128 + ncol]);
    A0z[kt] = r.v;
  }
#pragma unroll
  for (int s=0; s<3; ++s){
    union { bfrag v; unsigned short u[8]; } r;
#pragma unroll
    for (int j=0; j<8; ++j) r.u[j] = f2bf(W0[(size_t)(64 + s*32 + lg*8 + j)*128 + ncol]);
    A0c[s] = r.v;
  }
#pragma unroll
  for (int kt=0; kt<4; ++kt){
    union { bfrag v; unsigned short u[8]; } r1, r2, r3;
#pragma unroll
    for (int j=0; j<8; ++j){
      const int k = kt*32 + lg*8 + j;
      r1.u[j] = f2bf(W1[(size_t)k*128 + ncol]);
      r2.u[j] = f2bf(W2[(size_t)k*128 + ncol]);
      r3.u[j] = f2bf(Wo[(size_t)k*64 + ((w&3)*16 + lc)]);
    }
    A1f[kt] = r1.v; A2f[kt] = r2.v; Aof[kt] = r3.v;
  }
  float bd0[4], gd0[4], bed0[4];
  float bd1[4], gd1[4], bed1[4];
  float bd2[4], gd2[4], bed2[4];
  float bo_d[4];
#pragma unroll
  for (int g=0; g<4; ++g){
    const int n = nbase + g;
    bd0[g]=b0[n]; gd0[g]=g0[n]; bed0[g]=be0[n];
    bd1[g]=b1[n]; gd1[g]=g1[n]; bed1[g]=be1[n];
    bd2[g]=b2[n]; gd2[g]=g2[n]; bed2[g]=be2[n];
    bo_d[g] = bo[(nbase & 63) + g];
  }

  // ---- t pipeline (waves 0-3)
  const float* tp = tt + (size_t)(r0+lc)*NSEQ;
  float tcv = 0.f, tnv = 0.f;
  if (loW){ tcv = tp[0]; tnv = tp[1]; }

  // ---- z init (waves 0-3 cover all 64 latents x 16 rows)
  f4 zr = {0,0,0,0};
  if (loW){
    zr = *(const f4*)(z0 + (size_t)(r0+lc)*64 + nbase);
    *(f4*)(out + ((size_t)(r0+lc)*NSEQ)*64 + nbase) = zr;
    *(uint2*)(xin + lc*XS + nbase) = make_uint2(pk2bf(zr[0],zr[1]), pk2bf(zr[2],zr[3]));
  }

  // ---- cond(0) staged by waves 4-7; pf = cond(1)
  const int t4 = t & 255;
  const int srow = t4 >> 4, sq = t4 & 15;
  const float* cbase = cond + ((size_t)(r0+srow)*NSEQ)*96;
  float2 pf[3];
  if (!loW){
#pragma unroll
    for (int k2=0; k2<3; ++k2){
      const int s2 = (sq + 16*k2)*2;
      const float2 c = *(const float2*)(cbase + s2);
      *(uint32_t*)(xin + srow*XS + 64 + s2) = pk2bf(c.x, c.y);
      pf[k2] = *(const float2*)(cbase + 96 + s2);
    }
  }
  lds_barrier();

  // ---- prologue pre-acc of cond(0) (all waves)
  f4 apC;
  {
    const int o = lc*XS + 64 + lg*8;
    const bfrag c0 = *(const bfrag*)(xin + o);
    const bfrag c1 = *(const bfrag*)(xin + o + 32);
    const bfrag c2 = *(const bfrag*)(xin + o + 64);
    const f4 z4 = {0,0,0,0};
    apC = MFMA16(A0c[0], c0, z4, 0,0,0);
    apC = MFMA16(A0c[1], c1, apC, 0,0,0);
    apC = MFMA16(A0c[2], c2, apC, 0,0,0);
  }

  float h[4];
  for (int i=0; i<NSEQ-1; ++i){
    // ---- S_A: L0 z-part + cond(i+1) staging (waves 4-7) + t prefetch (waves 0-3)
    float tfv = 0.f;
    if (loW){
      const int ip2 = (i+2 <= NSEQ-1) ? (i+2) : (NSEQ-1);
      tfv = tp[ip2];
    }
    {
      const int o = lc*XS + lg*8;
      const bfrag bz0 = *(const bfrag*)(xin + o);
      const bfrag bz1 = *(const bfrag*)(xin + o + 32);
      const f4 z4 = {0,0,0,0};
      f4 c = MFMA16(A0z[0], bz0, z4, 0,0,0);
      c = MFMA16(A0z[1], bz1, c, 0,0,0);
#pragma unroll
      for (int g=0; g<4; ++g) h[g] = (c[g] + apC[g]) + bd0[g];
    }
    if (!loW){
#pragma unroll
      for (int k2=0; k2<3; ++k2){
        const int s2 = (sq + 16*k2)*2;
        *(uint32_t*)(xin + srow*XS + 64 + s2) = pk2bf(pf[k2].x, pf[k2].y);
      }
      if (i < NSEQ-2){
#pragma unroll
        for (int k2=0; k2<3; ++k2)
          pf[k2] = *(const float2*)(cbase + (size_t)(i+2)*96 + (sq + 16*k2)*2);
      }
    }
    stats_sq(h, part, w, lg, lc);
    lds_barrier();

    // ---- S_B: LN0
    ln_tanh_store(h, gd0, bed0, part, act, lg, lc, nbase);
    lds_barrier();

    // ---- S_C: L1
    layerK128(act, A1f, bd1, h, lg, lc);
    stats_sq(h, part, w, lg, lc);
    lds_barrier();

    // ---- S_D: LN1 + pre-acc cond(i+1)
    {
      const int o = lc*XS + 64 + lg*8;
      const bfrag c0 = *(const bfrag*)(xin + o);
      const bfrag c1 = *(const bfrag*)(xin + o + 32);
      const bfrag c2 = *(const bfrag*)(xin + o + 64);
      const f4 z4 = {0,0,0,0};
      f4 a = MFMA16(A0c[0], c0, z4, 0,0,0);
      a = MFMA16(A0c[1], c1, a, 0,0,0);
      a = MFMA16(A0c[2], c2, a, 0,0,0);
      ln_tanh_store(h, gd1, bed1, part, act, lg, lc, nbase);
      apC = a;
    }
    lds_barrier();

    // ---- S_E: L2
    layerK128(act, A2f, bd2, h, lg, lc);
    stats_sq(h, part, w, lg, lc);
    lds_barrier();

    // ---- S_F: LN2
    ln_tanh_store(h, gd2, bed2, part, act, lg, lc, nbase);
    lds_barrier();

    // ---- S_G: Lo + Euler + stores (waves 0-3 only; waves 4-7 idle frees SIMD)
    if (loW){
      const int o = lc*AS + lg*8;
      const bfrag b0f = *(const bfrag*)(act + o);
      const bfrag b1f = *(const bfrag*)(act + o + 32);
      const bfrag b2f = *(const bfrag*)(act + o + 64);
      const bfrag b3f = *(const bfrag*)(act + o + 96);
      const f4 z4 = {0,0,0,0};
      f4 aa = MFMA16(Aof[0], b0f, z4, 0,0,0);
      f4 ab = MFMA16(Aof[1], b1f, z4, 0,0,0);
      aa = MFMA16(Aof[2], b2f, aa, 0,0,0);
      ab = MFMA16(Aof[3], b3f, ab, 0,0,0);
      const float dt = tnv - tcv;
      f4 zn;
#pragma unroll
      for (int g=0; g<4; ++g) zn[g] = fmaf(dt, (aa[g]+ab[g]) + bo_d[g], zr[g]);
      zr = zn;
      *(f4*)(out + ((size_t)(r0+lc)*NSEQ + (size_t)(i+1))*64 + nbase) = zn;
      *(uint2*)(xin + lc*XS + nbase) = make_uint2(pk2bf(zn[0],zn[1]), pk2bf(zn[2],zn[3]));
      tcv = tnv; tnv = tfv;
    }
    lds_barrier();
  }
}

extern "C" void kernel_launch(void* const* d_in, const int* in_sizes, int n_in,
                              void* d_out, int out_size, void* d_ws, size_t ws_size,
                              hipStream_t stream) {
  const float* z0   = (const float*)d_in[0];
  const float* tt   = (const float*)d_in[1];
  const float* cond = (const float*)d_in[2];
  const float* W0   = (const float*)d_in[3];
  const float* b0   = (const float*)d_in[4];
  const float* g0   = (const float*)d_in[5];
  const float* be0  = (const float*)d_in[6];
  const float* W1   = (const float*)d_in[7];
  const float* b1   = (const float*)d_in[8];
  const float* g1   = (const float*)d_in[9];
  const float* be1  = (const float*)d_in[10];
  const float* W2   = (const float*)d_in[11];
  const float* b2   = (const float*)d_in[12];
  const float* g2   = (const float*)d_in[13];
  const float* be2  = (const float*)d_in[14];
  const float* Wo   = (const float*)d_in[15];
  const float* bo   = (const float*)d_in[16];
  float* out = (float*)d_out;

  hipLaunchKernelGGL(latent_ode_v8, dim3(64), dim3(512), 0, stream,
                     z0, tt, cond, W0, b0, g0, be0, W1, b1, g1, be1,
                     W2, b2, g2, be2, Wo, bo, out);
}

// Round 9
// 1111.575 us; speedup vs baseline: 2.0383x; 1.0134x over previous
//
#include <hip/hip_runtime.h>
#include <stdint.h>

#define NSEQ 512
#define XS 168   // xin row stride (shorts): [0:64 z][64:160 cond] + pad
#define AS 136   // act row stride (shorts)
#define PS 36    // part row stride (f32): 16 float2 slots + pad
#define EPS 1e-5f

typedef short bfrag __attribute__((ext_vector_type(8)));
typedef float f4 __attribute__((ext_vector_type(4)));
#define MFMA16 __builtin_amdgcn_mfma_f32_16x16x32_bf16

__device__ __forceinline__ unsigned short f2bf(float f){
  uint32_t u = __float_as_uint(f);
  u += 0x7FFFu + ((u>>16)&1u);   // RNE
  return (unsigned short)(u>>16);
}
__device__ __forceinline__ uint32_t pk2bf(float a, float b){
  uint32_t r;
  asm("v_cvt_pk_bf16_f32 %0, %1, %2" : "=v"(r) : "v"(a), "v"(b));
  return r;
}
__device__ __forceinline__ float tanh_fast(float v){
  float e = __builtin_amdgcn_exp2f(v * 2.8853900817779268f);  // e^(2v)
  float r = __builtin_amdgcn_rcpf(e + 1.f);
  return fmaf(-2.f, r, 1.f);
}
// LDS-only barrier: global loads/stores stay in flight across it
__device__ __forceinline__ void lds_barrier(){
  asm volatile("s_waitcnt lgkmcnt(0)" ::: "memory");
  __builtin_amdgcn_s_barrier();
  asm volatile("" ::: "memory");
}

// stats over lane's 8 neurons -> direct f2 write, 16 slots/row (no shuffles)
__device__ __forceinline__ void stats_write(const float (&h0)[4], const float (&h1)[4],
                                            float* __restrict__ part,
                                            const int w, const int lg, const int lc){
  const float s = ((h0[0]+h0[1])+(h0[2]+h0[3])) + ((h1[0]+h1[1])+(h1[2]+h1[3]));
  const float q = (fmaf(h0[0],h0[0], h0[1]*h0[1]) + fmaf(h0[2],h0[2], h0[3]*h0[3]))
                + (fmaf(h1[0],h1[0], h1[1]*h1[1]) + fmaf(h1[2],h1[2], h1[3]*h1[3]));
  *(float2*)(part + lc*PS + (w*4+lg)*2) = make_float2(s, q);
}

// LN + tanh + single-b128 act store (lane's 8 contiguous neurons w*32+lg*8+0..7)
__device__ __forceinline__ void ln_tanh_store(const float (&h0)[4], const float (&h1)[4],
    const float (&gd)[2][4], const float (&bed)[2][4],
    const float* __restrict__ part, unsigned short* __restrict__ actb,
    const int w, const int lg, const int lc){
  const float* pr = part + lc*PS;
  const f4 p0=*(const f4*)(pr),    p1=*(const f4*)(pr+4),  p2=*(const f4*)(pr+8),  p3=*(const f4*)(pr+12);
  const f4 p4=*(const f4*)(pr+16), p5=*(const f4*)(pr+20), p6=*(const f4*)(pr+24), p7=*(const f4*)(pr+28);
  const float ss = (((p0.x+p0.z)+(p1.x+p1.z)) + ((p2.x+p2.z)+(p3.x+p3.z)))
                 + (((p4.x+p4.z)+(p5.x+p5.z)) + ((p6.x+p6.z)+(p7.x+p7.z)));
  const float qq = (((p0.y+p0.w)+(p1.y+p1.w)) + ((p2.y+p2.w)+(p3.y+p3.w)))
                 + (((p4.y+p4.w)+(p5.y+p5.w)) + ((p6.y+p6.w)+(p7.y+p7.w)));
  const float mu = ss * 0.0078125f;
  const float rs = rsqrtf(fmaf(qq, 0.0078125f, -mu*mu) + EPS);
  float e0[4], e1[4];
#pragma unroll
  for (int g=0; g<4; ++g){
    e0[g] = tanh_fast(fmaf((h0[g]-mu)*rs, gd[0][g], bed[0][g]));
    e1[g] = tanh_fast(fmaf((h1[g]-mu)*rs, gd[1][g], bed[1][g]));
  }
  uint4 pk4;
  pk4.x = pk2bf(e0[0],e0[1]); pk4.y = pk2bf(e0[2],e0[3]);
  pk4.z = pk2bf(e1[0],e1[1]); pk4.w = pk2bf(e1[2],e1[3]);
  *(uint4*)(actb + lc*AS + w*32 + lg*8) = pk4;
}

__global__ __launch_bounds__(256, 1)
void latent_ode_v9(const float* __restrict__ z0, const float* __restrict__ tt,
                   const float* __restrict__ cond,
                   const float* __restrict__ W0, const float* __restrict__ b0,
                   const float* __restrict__ g0, const float* __restrict__ be0,
                   const float* __restrict__ W1, const float* __restrict__ b1,
                   const float* __restrict__ g1, const float* __restrict__ be1,
                   const float* __restrict__ W2, const float* __restrict__ b2,
                   const float* __restrict__ g2, const float* __restrict__ be2,
                   const float* __restrict__ Wo, const float* __restrict__ bo,
                   float* __restrict__ out)
{
  __shared__ __align__(16) unsigned short xin[16*XS];
  __shared__ __align__(16) unsigned short act[16*AS];
  __shared__ __align__(16) float part[16*PS];

  const int t  = threadIdx.x;     // 0..255, 4 waves
  const int w  = t >> 6;
  const int l  = t & 63;
  const int lg = l >> 4;
  const int lc = l & 15;
  const int r0 = blockIdx.x * 16;
  const int zcol = w*16 + lg*4;

  // ---- weight fragments (row permutation -> lane owns 8 contiguous neurons)
  bfrag A0z[2][2], A0c[2][3], A1f[2][4], A2f[2][4], Aof[4];
#pragma unroll
  for (int nt=0; nt<2; ++nt){
    const int col = w*32 + nt*4 + ((lc>>2)<<3) + (lc&3);
#pragma unroll
    for (int kt=0; kt<2; ++kt){
      union { bfrag v; unsigned short u[8]; } r;
#pragma unroll
      for (int j=0; j<8; ++j) r.u[j] = f2bf(W0[(size_t)(kt*32 + lg*8 + j)*128 + col]);
      A0z[nt][kt] = r.v;
    }
#pragma unroll
    for (int s=0; s<3; ++s){
      union { bfrag v; unsigned short u[8]; } r;
#pragma unroll
      for (int j=0; j<8; ++j) r.u[j] = f2bf(W0[(size_t)(64 + s*32 + lg*8 + j)*128 + col]);
      A0c[nt][s] = r.v;
    }
#pragma unroll
    for (int kt=0; kt<4; ++kt){
      union { bfrag v; unsigned short u[8]; } r1, r2;
#pragma unroll
      for (int j=0; j<8; ++j){
        const int k = kt*32 + lg*8 + j;
        r1.u[j] = f2bf(W1[(size_t)k*128 + col]);
        r2.u[j] = f2bf(W2[(size_t)k*128 + col]);
      }
      A1f[nt][kt] = r1.v; A2f[nt][kt] = r2.v;
    }
  }
#pragma unroll
  for (int kt=0; kt<4; ++kt){
    union { bfrag v; unsigned short u[8]; } r;
#pragma unroll
    for (int j=0; j<8; ++j)
      r.u[j] = f2bf(Wo[(size_t)(kt*32 + lg*8 + j)*64 + (w*16 + lc)]);
    Aof[kt] = r.v;
  }
  float bd0[2][4], gd0[2][4], bed0[2][4];
  float bd1[2][4], gd1[2][4], bed1[2][4];
  float bd2[2][4], gd2[2][4], bed2[2][4];
  float bo_d[4];
#pragma unroll
  for (int nt=0; nt<2; ++nt){
#pragma unroll
    for (int g=0; g<4; ++g){
      const int n = w*32 + lg*8 + nt*4 + g;
      bd0[nt][g]=b0[n]; gd0[nt][g]=g0[n]; bed0[nt][g]=be0[n];
      bd1[nt][g]=b1[n]; gd1[nt][g]=g1[n]; bed1[nt][g]=be1[n];
      bd2[nt][g]=b2[n]; gd2[nt][g]=g2[n]; bed2[nt][g]=be2[n];
    }
  }
#pragma unroll
  for (int g=0; g<4; ++g) bo_d[g] = bo[zcol + g];

  // ---- t pipeline (registers, one prefetch per step)
  const float* tp = tt + (size_t)(r0+lc)*NSEQ;
  float tcv = tp[0], tnv = tp[1];

  // ---- z init
  f4 zr;
  {
    const f4 zv = *(const f4*)(z0 + (size_t)(r0+lc)*64 + zcol);
    zr = zv;
    *(f4*)(out + ((size_t)(r0+lc)*NSEQ)*64 + zcol) = zv;
    *(uint2*)(xin + lc*XS + zcol) = make_uint2(pk2bf(zv[0],zv[1]), pk2bf(zv[2],zv[3]));
  }

  // ---- cond staging: 12 threads/row x 8 f32 -> one b128 bf16 write
  const bool stgW = (t < 192);
  const int srow = t / 12, s8 = t - srow*12;
  const float* cptr = cond + ((size_t)(r0+srow)*NSEQ)*96 + s8*8;
  float4 pf0 = {0,0,0,0}, pf1 = {0,0,0,0};
  if (stgW){
    const float4 c0 = *(const float4*)(cptr);
    const float4 c1 = *(const float4*)(cptr + 4);
    uint4 u;
    u.x = pk2bf(c0.x,c0.y); u.y = pk2bf(c0.z,c0.w);
    u.z = pk2bf(c1.x,c1.y); u.w = pk2bf(c1.z,c1.w);
    *(uint4*)(xin + srow*XS + 64 + s8*8) = u;
    pf0 = *(const float4*)(cptr + 96);
    pf1 = *(const float4*)(cptr + 100);
  }
  lds_barrier();

  // ---- prologue preacc of cond(0)
  f4 apC[2];
  {
    const int o = lc*XS + 64 + lg*8;
    const bfrag c0 = *(const bfrag*)(xin + o);
    const bfrag c1 = *(const bfrag*)(xin + o + 32);
    const bfrag c2 = *(const bfrag*)(xin + o + 64);
    const f4 z4 = {0,0,0,0};
#pragma unroll
    for (int nt=0; nt<2; ++nt){
      f4 a = MFMA16(A0c[nt][0], c0, z4, 0,0,0);
      a = MFMA16(A0c[nt][1], c1, a, 0,0,0);
      a = MFMA16(A0c[nt][2], c2, a, 0,0,0);
      apC[nt] = a;
    }
  }
  lds_barrier();   // protect cond(0) reads from step-0 staging overwrite

  float h0[4], h1[4];
  for (int i=0; i<NSEQ-1; ++i){
    // ---- S_A: L0 z-part + combine preacc; stats; stage cond(i+1); t prefetch
    const int ip2 = (i+2 <= NSEQ-1) ? (i+2) : (NSEQ-1);
    const float tfv = tp[ip2];
    {
      const int o = lc*XS + lg*8;
      const bfrag bz0 = *(const bfrag*)(xin + o);
      const bfrag bz1 = *(const bfrag*)(xin + o + 32);
      const f4 z4 = {0,0,0,0};
      f4 c0 = MFMA16(A0z[0][0], bz0, z4, 0,0,0);
      f4 c1 = MFMA16(A0z[1][0], bz0, z4, 0,0,0);
      c0 = MFMA16(A0z[0][1], bz1, c0, 0,0,0);
      c1 = MFMA16(A0z[1][1], bz1, c1, 0,0,0);
#pragma unroll
      for (int g=0; g<4; ++g){
        h0[g] = (c0[g] + apC[0][g]) + bd0[0][g];
        h1[g] = (c1[g] + apC[1][g]) + bd0[1][g];
      }
      stats_write(h0, h1, part, w, lg, lc);
    }
    if (stgW){
      uint4 u;
      u.x = pk2bf(pf0.x,pf0.y); u.y = pk2bf(pf0.z,pf0.w);
      u.z = pk2bf(pf1.x,pf1.y); u.w = pk2bf(pf1.z,pf1.w);
      *(uint4*)(xin + srow*XS + 64 + s8*8) = u;
      if (i < NSEQ-2){
        pf0 = *(const float4*)(cptr + (size_t)(i+2)*96);
        pf1 = *(const float4*)(cptr + (size_t)(i+2)*96 + 4);
      }
    }
    lds_barrier();

    // ---- S_B: LN0 + preacc cond(i+1)
    {
      const int o = lc*XS + 64 + lg*8;
      const bfrag c0 = *(const bfrag*)(xin + o);
      const bfrag c1 = *(const bfrag*)(xin + o + 32);
      const bfrag c2 = *(const bfrag*)(xin + o + 64);
      const f4 z4 = {0,0,0,0};
      f4 a0 = MFMA16(A0c[0][0], c0, z4, 0,0,0);
      f4 a1 = MFMA16(A0c[1][0], c0, z4, 0,0,0);
      a0 = MFMA16(A0c[0][1], c1, a0, 0,0,0);
      a1 = MFMA16(A0c[1][1], c1, a1, 0,0,0);
      a0 = MFMA16(A0c[0][2], c2, a0, 0,0,0);
      a1 = MFMA16(A0c[1][2], c2, a1, 0,0,0);
      ln_tanh_store(h0, h1, gd0, bed0, part, act, w, lg, lc);
      apC[0] = a0; apC[1] = a1;
    }
    lds_barrier();

    // ---- S_C: L1
    {
      const int o = lc*AS + lg*8;
      const bfrag b0f = *(const bfrag*)(act + o);
      const bfrag b1f = *(const bfrag*)(act + o + 32);
      const bfrag b2f = *(const bfrag*)(act + o + 64);
      const bfrag b3f = *(const bfrag*)(act + o + 96);
      const f4 z4 = {0,0,0,0};
      f4 ca0 = MFMA16(A1f[0][0], b0f, z4, 0,0,0);
      f4 cb0 = MFMA16(A1f[0][1], b1f, z4, 0,0,0);
      f4 ca1 = MFMA16(A1f[1][0], b0f, z4, 0,0,0);
      f4 cb1 = MFMA16(A1f[1][1], b1f, z4, 0,0,0);
      ca0 = MFMA16(A1f[0][2], b2f, ca0, 0,0,0);
      cb0 = MFMA16(A1f[0][3], b3f, cb0, 0,0,0);
      ca1 = MFMA16(A1f[1][2], b2f, ca1, 0,0,0);
      cb1 = MFMA16(A1f[1][3], b3f, cb1, 0,0,0);
#pragma unroll
      for (int g=0; g<4; ++g){
        h0[g] = (ca0[g]+cb0[g]) + bd1[0][g];
        h1[g] = (ca1[g]+cb1[g]) + bd1[1][g];
      }
      stats_write(h0, h1, part, w, lg, lc);
    }
    lds_barrier();

    // ---- S_D: LN1
    ln_tanh_store(h0, h1, gd1, bed1, part, act, w, lg, lc);
    lds_barrier();

    // ---- S_E: L2
    {
      const int o = lc*AS + lg*8;
      const bfrag b0f = *(const bfrag*)(act + o);
      const bfrag b1f = *(const bfrag*)(act + o + 32);
      const bfrag b2f = *(const bfrag*)(act + o + 64);
      const bfrag b3f = *(const bfrag*)(act + o + 96);
      const f4 z4 = {0,0,0,0};
      f4 ca0 = MFMA16(A2f[0][0], b0f, z4, 0,0,0);
      f4 cb0 = MFMA16(A2f[0][1], b1f, z4, 0,0,0);
      f4 ca1 = MFMA16(A2f[1][0], b0f, z4, 0,0,0);
      f4 cb1 = MFMA16(A2f[1][1], b1f, z4, 0,0,0);
      ca0 = MFMA16(A2f[0][2], b2f, ca0, 0,0,0);
      cb0 = MFMA16(A2f[0][3], b3f, cb0, 0,0,0);
      ca1 = MFMA16(A2f[1][2], b2f, ca1, 0,0,0);
      cb1 = MFMA16(A2f[1][3], b3f, cb1, 0,0,0);
#pragma unroll
      for (int g=0; g<4; ++g){
        h0[g] = (ca0[g]+cb0[g]) + bd2[0][g];
        h1[g] = (ca1[g]+cb1[g]) + bd2[1][g];
      }
      stats_write(h0, h1, part, w, lg, lc);
    }
    lds_barrier();

    // ---- S_F: LN2
    ln_tanh_store(h0, h1, gd2, bed2, part, act, w, lg, lc);
    lds_barrier();

    // ---- S_G: Lo + Euler + stores
    {
      const int o = lc*AS + lg*8;
      const bfrag b0f = *(const bfrag*)(act + o);
      const bfrag b1f = *(const bfrag*)(act + o + 32);
      const bfrag b2f = *(const bfrag*)(act + o + 64);
      const bfrag b3f = *(const bfrag*)(act + o + 96);
      const f4 z4 = {0,0,0,0};
      f4 aa = MFMA16(Aof[0], b0f, z4, 0,0,0);
      f4 ab = MFMA16(Aof[1], b1f, z4, 0,0,0);
      aa = MFMA16(Aof[2], b2f, aa, 0,0,0);
      ab = MFMA16(Aof[3], b3f, ab, 0,0,0);
      const float dt = tnv - tcv;
      f4 zn;
#pragma unroll
      for (int g=0; g<4; ++g) zn[g] = fmaf(dt, (aa[g]+ab[g]) + bo_d[g], zr[g]);
      zr = zn;
      *(f4*)(out + ((size_t)(r0+lc)*NSEQ + (size_t)(i+1))*64 + zcol) = zn;
      *(uint2*)(xin + lc*XS + zcol) = make_uint2(pk2bf(zn[0],zn[1]), pk2bf(zn[2],zn[3]));
      tcv = tnv; tnv = tfv;
    }
    lds_barrier();
  }
}

extern "C" void kernel_launch(void* const* d_in, const int* in_sizes, int n_in,
                              void* d_out, int out_size, void* d_ws, size_t ws_size,
                              hipStream_t stream) {
  const float* z0   = (const float*)d_in[0];
  const float* tt   = (const float*)d_in[1];
  const float* cond = (const float*)d_in[2];
  const float* W0   = (const float*)d_in[3];
  const float* b0   = (const float*)d_in[4];
  const float* g0   = (const float*)d_in[5];
  const float* be0  = (const float*)d_in[6];
  const float* W1   = (const float*)d_in[7];
  const float* b1   = (const float*)d_in[8];
  const float* g1   = (const float*)d_in[9];
  const float* be1  = (const float*)d_in[10];
  const float* W2   = (const float*)d_in[11];
  const float* b2   = (const float*)d_in[12];
  const float* g2   = (const float*)d_in[13];
  const float* be2  = (const float*)d_in[14];
  const float* Wo   = (const float*)d_in[15];
  const float* bo   = (const float*)d_in[16];
  float* out = (float*)d_out;

  hipLaunchKernelGGL(latent_ode_v9, dim3(64), dim3(256), 0, stream,
                     z0, tt, cond, W0, b0, g0, be0, W1, b1, g1, be1,
                     W2, b2, g2, be2, Wo, bo, out);
}